// Round 8
// baseline (151.727 us; speedup 1.0000x reference)
//
#include <hip/hip_runtime.h>

#define BN_EPS 1e-5f

typedef _Float16 half8 __attribute__((ext_vector_type(8)));
typedef float f32x4 __attribute__((ext_vector_type(4)));

__device__ __forceinline__ float tanh_fast(float x){
  float e = __expf(2.0f * x);
  return 1.0f - 2.0f / (e + 1.0f);
}

// LDS-only barrier: orders ds ops but leaves global loads IN FLIGHT (no vmcnt drain).
__device__ __forceinline__ void bar_lds(){
  asm volatile("s_waitcnt lgkmcnt(0)" ::: "memory");
  __builtin_amdgcn_s_barrier();
}

// ---------------- prep: W1 -> fp16 in MFMA-fragment order + BN scale/shift ----------------
// Fragment (q,c): q = k-chunk (32 k each, 0..7), c = col-block (16 e each, 0..15).
// lane l = kg*16+lr holds 8 halves: e = c*16+lr, d = q*32+kg*8+j.
__global__ __launch_bounds__(256) void k_prep(const float* __restrict__ W1,
    const float* __restrict__ gamma, const float* __restrict__ beta,
    const float* __restrict__ rmean, const float* __restrict__ rvar,
    _Float16* __restrict__ Bp2, float* __restrict__ bns, float* __restrict__ bnb){
  int i = blockIdx.x * 256 + threadIdx.x;   // 0..65535
  int j  = i & 7;
  int l  = (i >> 3) & 63;
  int c  = (i >> 9) & 15;
  int q  = (i >> 13) & 7;
  int lr = l & 15, kg = l >> 4;
  int e  = c * 16 + lr;
  int d  = q * 32 + kg * 8 + j;
  Bp2[i] = (_Float16)W1[e * 256 + d];
  if (i < 4096){
    float sc = gamma[i] * rsqrtf(rvar[i] + BN_EPS);
    bns[i] = sc;
    bnb[i] = beta[i] - rmean[i] * sc;
  }
}

// ---------------- persistent fused kernel: 4 chunks per block, cross-chunk pipeline ----------------
// 256 thr (4 waves), BM=64 x BN=256 per chunk, grid 1024 (4 blocks/CU resident).
// Per chunk: one 128-MFMA burst (full tile staged), then fused BN+tanh+dot epilogue,
// local softmax, and in-LDS weighted tile sum. Next chunk's global loads are issued
// under the current chunk's epilogue; barriers are lgkm-only so they stay in flight.
__global__ __launch_bounds__(256) void k_fused(const float* __restrict__ xh,
    const float* __restrict__ xhpre, const _Float16* __restrict__ Bp,
    const float* __restrict__ bns, const float* __restrict__ bnb,
    float* __restrict__ Pbuf, float2* __restrict__ mz){
  constexpr int S = 4096, Dd = 256;
  const int bid = blockIdx.x;       // 1024 = 64 b * 16 groups
  const int b   = bid >> 4;
  const int g   = bid & 15;
  const int cid0 = b * 64 + g * 4;  // first of 4 chunk ids
  const int tid = threadIdx.x;
  const int lane = tid & 63;
  const int w = tid >> 6;        // 0..3 = col-block owner
  const int kg = lane >> 4;      // 0..3
  const int lr = lane & 15;      // 0..15

  __shared__ _Float16 A[64 * 256];           // 32 KB, XOR-swizzled rows
  __shared__ float bnsc[64], bnsh[64];
  __shared__ float red[4][64];
  __shared__ f32x4 red4[4][64];
  __shared__ float wrow[64];
  char* Ab = (char*)A;

  float xhv[4];
  #pragma unroll
  for (int nt = 0; nt < 4; ++nt) xhv[nt] = xh[b * 256 + w * 64 + nt * 16 + lr];

  const float* bnsp = bns + g * 256;
  const float* bnbp = bnb + g * 256;
  const float* Abase = xhpre + ((size_t)b * S + (size_t)g * 256) * Dd;

  // staging map (per 64-col chunk c): rows w*16 + i*4 + kg, floats [c*64 + lr*4, +4)
#define ISSUE(buf, base, c) \
  _Pragma("unroll") \
  for (int i = 0; i < 4; ++i){ \
    int row = w * 16 + i * 4 + kg; \
    buf[i] = *reinterpret_cast<const float4*>((base) + (size_t)row * Dd + (c) * 64 + lr * 4); \
  }
#define CVTW(buf, c) \
  _Pragma("unroll") \
  for (int i = 0; i < 4; ++i){ \
    int row = w * 16 + i * 4 + kg; \
    union { _Float16 h[4]; uint2 u; } pk; \
    pk.h[0]=(_Float16)buf[i].x; pk.h[1]=(_Float16)buf[i].y; \
    pk.h[2]=(_Float16)buf[i].z; pk.h[3]=(_Float16)buf[i].w; \
    int byte = (row * 512 + (c) * 128 + lr * 8) ^ ((row & 7) << 4); \
    *reinterpret_cast<uint2*>(Ab + byte) = pk.u; \
  }

  float4 bufA[4], bufB[4], bufC[4], bufD[4];

  // ---- prologue: chunk 0 fully staged ----
  if (tid < 64){ bnsc[tid] = bnsp[tid]; bnsh[tid] = bnbp[tid]; }
  ISSUE(bufA, Abase, 0); ISSUE(bufB, Abase, 1); ISSUE(bufC, Abase, 2); ISSUE(bufD, Abase, 3);
  CVTW(bufA, 0); CVTW(bufB, 1); CVTW(bufC, 2); CVTW(bufD, 3);
  bar_lds();

  for (int j = 0; j < 4; ++j){
    const float* Anext = Abase + 64 * Dd;

    // ---- 128-MFMA burst over the full tile (q = 0..7) ----
    f32x4 acc[4][4] = {};
    #pragma unroll
    for (int q = 0; q < 8; ++q){
      half8 afr[4], bfr[4];
      #pragma unroll
      for (int nt = 0; nt < 4; ++nt)
        bfr[nt] = *reinterpret_cast<const half8*>(Bp + ((size_t)((q * 16 + w * 4 + nt) * 64 + lane)) * 8);
      #pragma unroll
      for (int mt = 0; mt < 4; ++mt){
        int row = mt * 16 + lr;
        int byte = (row * 512 + q * 64 + kg * 16) ^ ((row & 7) << 4);
        afr[mt] = *reinterpret_cast<const half8*>(Ab + byte);
      }
      #pragma unroll
      for (int mt = 0; mt < 4; ++mt)
        #pragma unroll
        for (int nt = 0; nt < 4; ++nt)
          acc[mt][nt] = __builtin_amdgcn_mfma_f32_16x16x32_f16(afr[mt], bfr[nt], acc[mt][nt], 0, 0, 0);
    }

    // issue first half of next chunk's loads (hidden under the a_t epilogue)
    if (j < 3){ ISSUE(bufA, Anext, 0); ISSUE(bufB, Anext, 1); }

    // ---- a_t epilogue: BN + tanh + dot(x_h); reduce 16 cols (lr) per wave ----
    #pragma unroll
    for (int mt = 0; mt < 4; ++mt){
      #pragma unroll
      for (int r = 0; r < 4; ++r){
        int row = mt * 16 + kg * 4 + r;   // C/D: col=lane&15, row=(lane>>4)*4+reg
        float sc = bnsc[row], sh = bnsh[row];
        float sum = 0.f;
        #pragma unroll
        for (int nt = 0; nt < 4; ++nt){
          float hv = fmaf(acc[mt][nt][r], sc, sh);
          sum = fmaf(tanh_fast(hv), xhv[nt], sum);
        }
        sum += __shfl_xor(sum, 1);
        sum += __shfl_xor(sum, 2);
        sum += __shfl_xor(sum, 4);
        sum += __shfl_xor(sum, 8);
        if (lr == 0) red[w][row] = sum;
      }
    }
    bar_lds();

    // issue second half of next chunk's loads (acc is dead now)
    if (j < 3){ ISSUE(bufC, Anext, 2); ISSUE(bufD, Anext, 3); }

    // ---- local softmax stats over 64 rows (wave 0) ----
    if (w == 0){
      float v = red[0][lane] + red[1][lane] + red[2][lane] + red[3][lane];
      float m_c = v;
      #pragma unroll
      for (int o = 1; o < 64; o <<= 1) m_c = fmaxf(m_c, __shfl_xor(m_c, o));
      float wv = __expf(v - m_c);
      wrow[lane] = wv;
      float z_c = wv;
      #pragma unroll
      for (int o = 1; o < 64; o <<= 1) z_c += __shfl_xor(z_c, o);
      if (lane == 0) mz[cid0 + j] = make_float2(m_c, z_c);
    }
    bar_lds();

    // ---- weighted tile sum: P_c[d] = sum_rows wrow[row]*x[row][d], from LDS fp16 ----
    f32x4 pacc = {0.f, 0.f, 0.f, 0.f};
    #pragma unroll
    for (int r = 0; r < 16; ++r){
      int row = w * 16 + r;
      float wgt = wrow[row];
      int byte = (row * 512 + lane * 8) ^ ((row & 7) << 4);
      union { _Float16 h[4]; uint2 u; } pk;
      pk.u = *reinterpret_cast<const uint2*>(Ab + byte);
      pacc[0] = fmaf(wgt, (float)pk.h[0], pacc[0]);
      pacc[1] = fmaf(wgt, (float)pk.h[1], pacc[1]);
      pacc[2] = fmaf(wgt, (float)pk.h[2], pacc[2]);
      pacc[3] = fmaf(wgt, (float)pk.h[3], pacc[3]);
    }
    red4[w][lane] = pacc;
    bar_lds();                       // red4 ready; all A-tile reads of chunk j done

    if (tid < 64){
      f32x4 r = red4[0][tid] + red4[1][tid] + red4[2][tid] + red4[3][tid];
      *reinterpret_cast<f32x4*>(Pbuf + (size_t)(cid0 + j) * 256 + tid * 4) = r;
    }

    if (j < 3){
      // stage next chunk into (now free) A tile; refresh BN constants
      CVTW(bufA, 0); CVTW(bufB, 1); CVTW(bufC, 2); CVTW(bufD, 3);
      if (tid < 64){
        bnsc[tid] = bnsp[(j + 1) * 64 + tid];
        bnsh[tid] = bnbp[(j + 1) * 64 + tid];
      }
      bar_lds();
      Abase = Anext;
    }
  }
#undef ISSUE
#undef CVTW
}

// ---------------- combine 64 chunks per b: flash-style merge + W2 scale ----------------
__global__ __launch_bounds__(256) void k_combine(const float* __restrict__ Pbuf,
    const float2* __restrict__ mz, const float* __restrict__ W2, float* __restrict__ out){
  int b = blockIdx.x, d = threadIdx.x;
  __shared__ float2 smz[64];
  if (d < 64) smz[d] = mz[b * 64 + d];
  __syncthreads();
  float M = smz[0].x;
  #pragma unroll
  for (int c = 1; c < 64; ++c) M = fmaxf(M, smz[c].x);
  float Z = 0.f, acc = 0.f;
  #pragma unroll 8
  for (int c = 0; c < 64; ++c){
    float e = __expf(smz[c].x - M);
    Z += smz[c].y * e;
    acc = fmaf(e, Pbuf[(size_t)(b * 64 + c) * 256 + d], acc);
  }
  out[b * 256 + d] = acc * W2[d] / Z;
}

extern "C" void kernel_launch(void* const* d_in, const int* in_sizes, int n_in,
                              void* d_out, int out_size, void* d_ws, size_t ws_size,
                              hipStream_t stream){
  const float* x_h    = (const float*)d_in[0];
  const float* x_hpre = (const float*)d_in[1];
  const float* W1     = (const float*)d_in[2];
  const float* W2     = (const float*)d_in[3];
  const float* gamma  = (const float*)d_in[4];
  const float* beta   = (const float*)d_in[5];
  const float* rmean  = (const float*)d_in[6];
  const float* rvar   = (const float*)d_in[7];
  float* out = (float*)d_out;

  char* ws = (char*)d_ws;
  _Float16* Bp = (_Float16*)(ws);            // 131072 B (fragment-ordered W1)
  float* bns   = (float*)(ws + 131072);      // 16 KB
  float* bnb   = (float*)(ws + 147456);      // 16 KB
  float* Pbuf  = (float*)(ws + 163840);      // 4 MB (64*64 chunks * 256 f32)
  float2* mzb  = (float2*)(ws + 4358144);    // 32 KB  (total ~4.4 MB)

  hipLaunchKernelGGL(k_prep,    dim3(256),  dim3(256), 0, stream, W1, gamma, beta, rmean, rvar, Bp, bns, bnb);
  hipLaunchKernelGGL(k_fused,   dim3(1024), dim3(256), 0, stream, x_h, x_hpre, Bp, bns, bnb, Pbuf, mzb);
  hipLaunchKernelGGL(k_combine, dim3(64),   dim3(256), 0, stream, Pbuf, mzb, W2, out);
}

// Round 10
// 144.896 us; speedup vs baseline: 1.0471x; 1.0471x over previous
//
#include <hip/hip_runtime.h>

#define BN_EPS 1e-5f

typedef _Float16 half8 __attribute__((ext_vector_type(8)));
typedef __fp16 fp16x2 __attribute__((ext_vector_type(2)));
typedef float f32x4 __attribute__((ext_vector_type(4)));

__device__ __forceinline__ float tanh_fast(float x){
  float e = __expf(2.0f * x);
  return 1.0f - 2.0f / (e + 1.0f);
}

// LDS-only barrier: orders ds ops but leaves global loads IN FLIGHT (no vmcnt drain).
__device__ __forceinline__ void bar_lds(){
  asm volatile("s_waitcnt lgkmcnt(0)" ::: "memory");
  __builtin_amdgcn_s_barrier();
}

// ---------------- prep: W1 -> fp16 in MFMA-fragment order + BN scale/shift ----------------
// Fragment (q,c): q = k-chunk (32 k each, 0..7), c = col-block (16 e each, 0..15).
// lane l = kg*16+lr holds 8 halves: e = c*16+lr, d = q*32+kg*8+j.
__global__ __launch_bounds__(256) void k_prep(const float* __restrict__ W1,
    const float* __restrict__ gamma, const float* __restrict__ beta,
    const float* __restrict__ rmean, const float* __restrict__ rvar,
    _Float16* __restrict__ Bp2, float* __restrict__ bns, float* __restrict__ bnb){
  int i = blockIdx.x * 256 + threadIdx.x;   // 0..65535
  int j  = i & 7;
  int l  = (i >> 3) & 63;
  int c  = (i >> 9) & 15;
  int q  = (i >> 13) & 7;
  int lr = l & 15, kg = l >> 4;
  int e  = c * 16 + lr;
  int d  = q * 32 + kg * 8 + j;
  Bp2[i] = (_Float16)W1[e * 256 + d];
  if (i < 4096){
    float sc = gamma[i] * rsqrtf(rvar[i] + BN_EPS);
    bns[i] = sc;
    bnb[i] = beta[i] - rmean[i] * sc;
  }
}

// ---------------- fused GEMM + BN + tanh + dot(x_h) + local softmax + weighted tile sum ----------------
// R5 structure (best: 97.8us): 256 thr (4 waves), BM=64 x BN=256, K=256 as 2 steps
// of BK=128; chunks c2,c3 in flight across the lgkm-only prologue barrier.
// This round: q=0 B-prefetch before the barrier, setprio around MFMA clusters,
// all-wave redundant softmax (one barrier fewer, no wrow LDS), pkrtz staging cvt.
__global__ void k_fused(const float* __restrict__ xh,
    const float* __restrict__ xhpre, const _Float16* __restrict__ Bp,
    const float* __restrict__ bns, const float* __restrict__ bnb,
    float* __restrict__ Pbuf, float2* __restrict__ mz){
  constexpr int S = 4096, Dd = 256;
  const int bid = blockIdx.x;       // 64 b * 64 chunks
  const int b  = bid >> 6;
  const int s0 = (bid & 63) * 64;
  const int tid = threadIdx.x;
  const int lane = tid & 63;
  const int w = tid >> 6;        // 0..3 = col-block owner
  const int kg = lane >> 4;      // 0..3
  const int lr = lane & 15;      // 0..15

  __shared__ _Float16 A[64 * 256];           // 32 KB, XOR-swizzled rows
  __shared__ float bnsc[64], bnsh[64];
  __shared__ float red[4][64];
  __shared__ f32x4 red4[4][64];              // 4 KB
  char* Ab = (char*)A;

  if (tid < 64){ bnsc[tid] = bns[s0 + tid]; bnsh[tid] = bnb[s0 + tid]; }

  float xhv[4];
  #pragma unroll
  for (int nt = 0; nt < 4; ++nt) xhv[nt] = xh[b * 256 + w * 64 + nt * 16 + lr];

  const float* Abase = xhpre + ((size_t)b * S + s0) * Dd;

  // per-thread staging rows: w*16 + i*4 + kg, floats [c*64 + lr*4, +4)
#define ISSUE(buf, c) \
  _Pragma("unroll") \
  for (int i = 0; i < 4; ++i){ \
    int row = w * 16 + i * 4 + kg; \
    buf[i] = *reinterpret_cast<const float4*>(Abase + (size_t)row * Dd + (c) * 64 + lr * 4); \
  }
#define CVTW(buf, c) \
  _Pragma("unroll") \
  for (int i = 0; i < 4; ++i){ \
    int row = w * 16 + i * 4 + kg; \
    union { fp16x2 h2[2]; uint2 u; } pk; \
    pk.h2[0] = __builtin_amdgcn_cvt_pkrtz(buf[i].x, buf[i].y); \
    pk.h2[1] = __builtin_amdgcn_cvt_pkrtz(buf[i].z, buf[i].w); \
    int byte = (row * 512 + (c) * 128 + lr * 8) ^ ((row & 7) << 4); \
    *reinterpret_cast<uint2*>(Ab + byte) = pk.u; \
  }

  // prefetch q=0 B-fragments (L2) so the first MFMA cluster starts immediately
  half8 bfr0[4];
  #pragma unroll
  for (int nt = 0; nt < 4; ++nt)
    bfr0[nt] = *reinterpret_cast<const half8*>(Bp + ((size_t)((w * 4 + nt) * 64 + lane)) * 8);

  float4 bufA[4], bufB[4], bufC[4], bufD[4];
  ISSUE(bufA, 0); ISSUE(bufB, 1);
  CVTW(bufA, 0);  ISSUE(bufC, 2);
  CVTW(bufB, 1);  ISSUE(bufD, 3);
  // barrier 1: orders LDS writes only; c2,c3 (and bfr0) remain in flight
  bar_lds();

  f32x4 acc[4][4] = {};

  // ---- step A: q = 0 (prefetched B) ----
  {
    half8 afr[4];
    #pragma unroll
    for (int mt = 0; mt < 4; ++mt){
      int row = mt * 16 + lr;
      int byte = (row * 512 + kg * 16) ^ ((row & 7) << 4);
      afr[mt] = *reinterpret_cast<const half8*>(Ab + byte);
    }
    __builtin_amdgcn_s_setprio(1);
    #pragma unroll
    for (int mt = 0; mt < 4; ++mt)
      #pragma unroll
      for (int nt = 0; nt < 4; ++nt)
        acc[mt][nt] = __builtin_amdgcn_mfma_f32_16x16x32_f16(afr[mt], bfr0[nt], acc[mt][nt], 0, 0, 0);
    __builtin_amdgcn_s_setprio(0);
  }
  // ---- step A: q = 1..3 ----
  #pragma unroll
  for (int q = 1; q < 4; ++q){
    half8 afr[4], bfr[4];
    #pragma unroll
    for (int nt = 0; nt < 4; ++nt)
      bfr[nt] = *reinterpret_cast<const half8*>(Bp + ((size_t)((q * 16 + w * 4 + nt) * 64 + lane)) * 8);
    #pragma unroll
    for (int mt = 0; mt < 4; ++mt){
      int row = mt * 16 + lr;
      int byte = (row * 512 + q * 64 + kg * 16) ^ ((row & 7) << 4);
      afr[mt] = *reinterpret_cast<const half8*>(Ab + byte);
    }
    __builtin_amdgcn_s_setprio(1);
    #pragma unroll
    for (int mt = 0; mt < 4; ++mt)
      #pragma unroll
      for (int nt = 0; nt < 4; ++nt)
        acc[mt][nt] = __builtin_amdgcn_mfma_f32_16x16x32_f16(afr[mt], bfr[nt], acc[mt][nt], 0, 0, 0);
    __builtin_amdgcn_s_setprio(0);
  }

  // write step-B columns (vmcnt wait on c2/c3 here; disjoint LDS columns)
  CVTW(bufC, 2); CVTW(bufD, 3);
  bar_lds();

  // ---- step B: q = 4..7 ----
  #pragma unroll
  for (int q = 4; q < 8; ++q){
    half8 afr[4], bfr[4];
    #pragma unroll
    for (int nt = 0; nt < 4; ++nt)
      bfr[nt] = *reinterpret_cast<const half8*>(Bp + ((size_t)((q * 16 + w * 4 + nt) * 64 + lane)) * 8);
    #pragma unroll
    for (int mt = 0; mt < 4; ++mt){
      int row = mt * 16 + lr;
      int byte = (row * 512 + q * 64 + kg * 16) ^ ((row & 7) << 4);
      afr[mt] = *reinterpret_cast<const half8*>(Ab + byte);
    }
    __builtin_amdgcn_s_setprio(1);
    #pragma unroll
    for (int mt = 0; mt < 4; ++mt)
      #pragma unroll
      for (int nt = 0; nt < 4; ++nt)
        acc[mt][nt] = __builtin_amdgcn_mfma_f32_16x16x32_f16(afr[mt], bfr[nt], acc[mt][nt], 0, 0, 0);
    __builtin_amdgcn_s_setprio(0);
  }
#undef ISSUE
#undef CVTW

  // ---- a_t epilogue: BN + tanh + dot(x_h); reduce 16 cols (lr) per wave ----
  #pragma unroll
  for (int mt = 0; mt < 4; ++mt){
    #pragma unroll
    for (int r = 0; r < 4; ++r){
      int row = mt * 16 + kg * 4 + r;   // C/D: col=lane&15, row=(lane>>4)*4+reg
      float sc = bnsc[row], sh = bnsh[row];
      float sum = 0.f;
      #pragma unroll
      for (int nt = 0; nt < 4; ++nt){
        float hv = fmaf(acc[mt][nt][r], sc, sh);
        sum = fmaf(tanh_fast(hv), xhv[nt], sum);
      }
      sum += __shfl_xor(sum, 1);
      sum += __shfl_xor(sum, 2);
      sum += __shfl_xor(sum, 4);
      sum += __shfl_xor(sum, 8);
      if (lr == 0) red[w][row] = sum;
    }
  }
  bar_lds();

  // ---- softmax stats, computed redundantly by ALL waves (no extra barrier) ----
  float v = red[0][lane] + red[1][lane] + red[2][lane] + red[3][lane];
  float m_c = v;
  #pragma unroll
  for (int o = 1; o < 64; o <<= 1) m_c = fmaxf(m_c, __shfl_xor(m_c, o));
  float wv = __expf(v - m_c);    // this lane's weight for s-row `lane`
  float z_c = wv;
  #pragma unroll
  for (int o = 1; o < 64; o <<= 1) z_c += __shfl_xor(z_c, o);
  if (tid == 0) mz[bid] = make_float2(m_c, z_c);

  // ---- weighted tile sum: P_c[d] = sum_rows wgt[row]*x[row][d], from LDS fp16 ----
  f32x4 pacc = {0.f, 0.f, 0.f, 0.f};
  #pragma unroll
  for (int r = 0; r < 16; ++r){
    int row = w * 16 + r;
    float wgt = __shfl(wv, row);
    int byte = (row * 512 + lane * 8) ^ ((row & 7) << 4);
    union { _Float16 h[4]; uint2 u; } pk;
    pk.u = *reinterpret_cast<const uint2*>(Ab + byte);
    pacc[0] = fmaf(wgt, (float)pk.h[0], pacc[0]);
    pacc[1] = fmaf(wgt, (float)pk.h[1], pacc[1]);
    pacc[2] = fmaf(wgt, (float)pk.h[2], pacc[2]);
    pacc[3] = fmaf(wgt, (float)pk.h[3], pacc[3]);
  }
  red4[w][lane] = pacc;
  bar_lds();
  if (tid < 64){
    f32x4 r = red4[0][tid] + red4[1][tid] + red4[2][tid] + red4[3][tid];
    *reinterpret_cast<f32x4*>(Pbuf + (size_t)bid * 256 + tid * 4) = r;
  }
}

// ---------------- combine 64 chunks per b: flash-style merge + W2 scale ----------------
__global__ __launch_bounds__(256) void k_combine(const float* __restrict__ Pbuf,
    const float2* __restrict__ mz, const float* __restrict__ W2, float* __restrict__ out){
  int b = blockIdx.x, d = threadIdx.x;
  __shared__ float2 smz[64];
  if (d < 64) smz[d] = mz[b * 64 + d];
  __syncthreads();
  float M = smz[0].x;
  #pragma unroll
  for (int c = 1; c < 64; ++c) M = fmaxf(M, smz[c].x);
  float Z = 0.f, acc = 0.f;
  #pragma unroll 8
  for (int c = 0; c < 64; ++c){
    float e = __expf(smz[c].x - M);
    Z += smz[c].y * e;
    acc = fmaf(e, Pbuf[(size_t)(b * 64 + c) * 256 + d], acc);
  }
  out[b * 256 + d] = acc * W2[d] / Z;
}

extern "C" void kernel_launch(void* const* d_in, const int* in_sizes, int n_in,
                              void* d_out, int out_size, void* d_ws, size_t ws_size,
                              hipStream_t stream){
  const float* x_h    = (const float*)d_in[0];
  const float* x_hpre = (const float*)d_in[1];
  const float* W1     = (const float*)d_in[2];
  const float* W2     = (const float*)d_in[3];
  const float* gamma  = (const float*)d_in[4];
  const float* beta   = (const float*)d_in[5];
  const float* rmean  = (const float*)d_in[6];
  const float* rvar   = (const float*)d_in[7];
  float* out = (float*)d_out;

  char* ws = (char*)d_ws;
  _Float16* Bp = (_Float16*)(ws);            // 131072 B (fragment-ordered W1)
  float* bns   = (float*)(ws + 131072);      // 16 KB
  float* bnb   = (float*)(ws + 147456);      // 16 KB
  float* Pbuf  = (float*)(ws + 163840);      // 4 MB (64*64 chunks * 256 f32)
  float2* mzb  = (float2*)(ws + 4358144);    // 32 KB  (total ~4.4 MB)

  hipLaunchKernelGGL(k_prep,    dim3(256),  dim3(256), 0, stream, W1, gamma, beta, rmean, rvar, Bp, bns, bnb);
  hipLaunchKernelGGL(k_fused,   dim3(4096), dim3(256), 0, stream, x_h, x_hpre, Bp, bns, bnb, Pbuf, mzb);
  hipLaunchKernelGGL(k_combine, dim3(64),   dim3(256), 0, stream, Pbuf, mzb, W2, out);
}

// Round 11
// 121.323 us; speedup vs baseline: 1.2506x; 1.1943x over previous
//
#include <hip/hip_runtime.h>

#define BN_EPS 1e-5f

typedef _Float16 half8 __attribute__((ext_vector_type(8)));
typedef __fp16 fp16x2 __attribute__((ext_vector_type(2)));
typedef float f32x4 __attribute__((ext_vector_type(4)));

__device__ __forceinline__ float tanh_fast(float x){
  float e = __expf(2.0f * x);
  return 1.0f - 2.0f / (e + 1.0f);
}

// LDS-only barrier: orders ds ops but leaves global loads IN FLIGHT (no vmcnt drain).
__device__ __forceinline__ void bar_lds(){
  asm volatile("s_waitcnt lgkmcnt(0)" ::: "memory");
  __builtin_amdgcn_s_barrier();
}

// ---------------- prep: W1 -> fp16 in MFMA-fragment order + BN scale/shift ----------------
// Fragment (q,c): q = k-chunk (32 k each, 0..7), c = col-block (16 e each, 0..15).
// lane l = kg*16+lr holds 8 halves: e = c*16+lr, d = q*32+kg*8+j.
__global__ __launch_bounds__(256) void k_prep(const float* __restrict__ W1,
    const float* __restrict__ gamma, const float* __restrict__ beta,
    const float* __restrict__ rmean, const float* __restrict__ rvar,
    _Float16* __restrict__ Bp2, float* __restrict__ bns, float* __restrict__ bnb){
  int i = blockIdx.x * 256 + threadIdx.x;   // 0..65535
  int j  = i & 7;
  int l  = (i >> 3) & 63;
  int c  = (i >> 9) & 15;
  int q  = (i >> 13) & 7;
  int lr = l & 15, kg = l >> 4;
  int e  = c * 16 + lr;
  int d  = q * 32 + kg * 8 + j;
  Bp2[i] = (_Float16)W1[e * 256 + d];
  if (i < 4096){
    float sc = gamma[i] * rsqrtf(rvar[i] + BN_EPS);
    bns[i] = sc;
    bnb[i] = beta[i] - rmean[i] * sc;
  }
}

// ---------------- fused GEMM + BN + tanh + dot(x_h) + local softmax + weighted tile sum ----------------
// R5 structure (97.8us): 256 thr (4 waves), BM=64 x BN=256, K=256 as 2 steps of
// BK=128; chunks c2,c3 in flight across the lgkm-only prologue barrier.
// + q=0 B-prefetch, setprio around MFMA clusters, all-wave redundant softmax,
// pkrtz staging cvt. launch_bounds(256) REQUIRED: without it the compiler caps
// VGPR at 64 and spills ~50 regs (round-10 regression: WRITE_SIZE 135MB).
__global__ __launch_bounds__(256) void k_fused(const float* __restrict__ xh,
    const float* __restrict__ xhpre, const _Float16* __restrict__ Bp,
    const float* __restrict__ bns, const float* __restrict__ bnb,
    float* __restrict__ Pbuf, float2* __restrict__ mz){
  constexpr int S = 4096, Dd = 256;
  const int bid = blockIdx.x;       // 64 b * 64 chunks
  const int b  = bid >> 6;
  const int s0 = (bid & 63) * 64;
  const int tid = threadIdx.x;
  const int lane = tid & 63;
  const int w = tid >> 6;        // 0..3 = col-block owner
  const int kg = lane >> 4;      // 0..3
  const int lr = lane & 15;      // 0..15

  __shared__ _Float16 A[64 * 256];           // 32 KB, XOR-swizzled rows
  __shared__ float bnsc[64], bnsh[64];
  __shared__ float red[4][64];
  __shared__ f32x4 red4[4][64];              // 4 KB
  char* Ab = (char*)A;

  if (tid < 64){ bnsc[tid] = bns[s0 + tid]; bnsh[tid] = bnb[s0 + tid]; }

  float xhv[4];
  #pragma unroll
  for (int nt = 0; nt < 4; ++nt) xhv[nt] = xh[b * 256 + w * 64 + nt * 16 + lr];

  const float* Abase = xhpre + ((size_t)b * S + s0) * Dd;

  // per-thread staging rows: w*16 + i*4 + kg, floats [c*64 + lr*4, +4)
#define ISSUE(buf, c) \
  _Pragma("unroll") \
  for (int i = 0; i < 4; ++i){ \
    int row = w * 16 + i * 4 + kg; \
    buf[i] = *reinterpret_cast<const float4*>(Abase + (size_t)row * Dd + (c) * 64 + lr * 4); \
  }
#define CVTW(buf, c) \
  _Pragma("unroll") \
  for (int i = 0; i < 4; ++i){ \
    int row = w * 16 + i * 4 + kg; \
    union { fp16x2 h2[2]; uint2 u; } pk; \
    pk.h2[0] = __builtin_amdgcn_cvt_pkrtz(buf[i].x, buf[i].y); \
    pk.h2[1] = __builtin_amdgcn_cvt_pkrtz(buf[i].z, buf[i].w); \
    int byte = (row * 512 + (c) * 128 + lr * 8) ^ ((row & 7) << 4); \
    *reinterpret_cast<uint2*>(Ab + byte) = pk.u; \
  }

  // prefetch q=0 B-fragments (L2) so the first MFMA cluster starts immediately
  half8 bfr0[4];
  #pragma unroll
  for (int nt = 0; nt < 4; ++nt)
    bfr0[nt] = *reinterpret_cast<const half8*>(Bp + ((size_t)((w * 4 + nt) * 64 + lane)) * 8);

  float4 bufA[4], bufB[4], bufC[4], bufD[4];
  ISSUE(bufA, 0); ISSUE(bufB, 1);
  CVTW(bufA, 0);  ISSUE(bufC, 2);
  CVTW(bufB, 1);  ISSUE(bufD, 3);
  // barrier 1: orders LDS writes only; c2,c3 (and bfr0) remain in flight
  bar_lds();

  f32x4 acc[4][4] = {};

  // ---- step A: q = 0 (prefetched B) ----
  {
    half8 afr[4];
    #pragma unroll
    for (int mt = 0; mt < 4; ++mt){
      int row = mt * 16 + lr;
      int byte = (row * 512 + kg * 16) ^ ((row & 7) << 4);
      afr[mt] = *reinterpret_cast<const half8*>(Ab + byte);
    }
    __builtin_amdgcn_s_setprio(1);
    #pragma unroll
    for (int mt = 0; mt < 4; ++mt)
      #pragma unroll
      for (int nt = 0; nt < 4; ++nt)
        acc[mt][nt] = __builtin_amdgcn_mfma_f32_16x16x32_f16(afr[mt], bfr0[nt], acc[mt][nt], 0, 0, 0);
    __builtin_amdgcn_s_setprio(0);
  }
  // ---- step A: q = 1..3 ----
  #pragma unroll
  for (int q = 1; q < 4; ++q){
    half8 afr[4], bfr[4];
    #pragma unroll
    for (int nt = 0; nt < 4; ++nt)
      bfr[nt] = *reinterpret_cast<const half8*>(Bp + ((size_t)((q * 16 + w * 4 + nt) * 64 + lane)) * 8);
    #pragma unroll
    for (int mt = 0; mt < 4; ++mt){
      int row = mt * 16 + lr;
      int byte = (row * 512 + q * 64 + kg * 16) ^ ((row & 7) << 4);
      afr[mt] = *reinterpret_cast<const half8*>(Ab + byte);
    }
    __builtin_amdgcn_s_setprio(1);
    #pragma unroll
    for (int mt = 0; mt < 4; ++mt)
      #pragma unroll
      for (int nt = 0; nt < 4; ++nt)
        acc[mt][nt] = __builtin_amdgcn_mfma_f32_16x16x32_f16(afr[mt], bfr[nt], acc[mt][nt], 0, 0, 0);
    __builtin_amdgcn_s_setprio(0);
  }

  // write step-B columns (vmcnt wait on c2/c3 here; disjoint LDS columns)
  CVTW(bufC, 2); CVTW(bufD, 3);
  bar_lds();

  // ---- step B: q = 4..7 ----
  #pragma unroll
  for (int q = 4; q < 8; ++q){
    half8 afr[4], bfr[4];
    #pragma unroll
    for (int nt = 0; nt < 4; ++nt)
      bfr[nt] = *reinterpret_cast<const half8*>(Bp + ((size_t)((q * 16 + w * 4 + nt) * 64 + lane)) * 8);
    #pragma unroll
    for (int mt = 0; mt < 4; ++mt){
      int row = mt * 16 + lr;
      int byte = (row * 512 + q * 64 + kg * 16) ^ ((row & 7) << 4);
      afr[mt] = *reinterpret_cast<const half8*>(Ab + byte);
    }
    __builtin_amdgcn_s_setprio(1);
    #pragma unroll
    for (int mt = 0; mt < 4; ++mt)
      #pragma unroll
      for (int nt = 0; nt < 4; ++nt)
        acc[mt][nt] = __builtin_amdgcn_mfma_f32_16x16x32_f16(afr[mt], bfr[nt], acc[mt][nt], 0, 0, 0);
    __builtin_amdgcn_s_setprio(0);
  }
#undef ISSUE
#undef CVTW

  // ---- a_t epilogue: BN + tanh + dot(x_h); reduce 16 cols (lr) per wave ----
  #pragma unroll
  for (int mt = 0; mt < 4; ++mt){
    #pragma unroll
    for (int r = 0; r < 4; ++r){
      int row = mt * 16 + kg * 4 + r;   // C/D: col=lane&15, row=(lane>>4)*4+reg
      float sc = bnsc[row], sh = bnsh[row];
      float sum = 0.f;
      #pragma unroll
      for (int nt = 0; nt < 4; ++nt){
        float hv = fmaf(acc[mt][nt][r], sc, sh);
        sum = fmaf(tanh_fast(hv), xhv[nt], sum);
      }
      sum += __shfl_xor(sum, 1);
      sum += __shfl_xor(sum, 2);
      sum += __shfl_xor(sum, 4);
      sum += __shfl_xor(sum, 8);
      if (lr == 0) red[w][row] = sum;
    }
  }
  bar_lds();

  // ---- softmax stats, computed redundantly by ALL waves (no extra barrier) ----
  float v = red[0][lane] + red[1][lane] + red[2][lane] + red[3][lane];
  float m_c = v;
  #pragma unroll
  for (int o = 1; o < 64; o <<= 1) m_c = fmaxf(m_c, __shfl_xor(m_c, o));
  float wv = __expf(v - m_c);    // this lane's weight for s-row `lane`
  float z_c = wv;
  #pragma unroll
  for (int o = 1; o < 64; o <<= 1) z_c += __shfl_xor(z_c, o);
  if (tid == 0) mz[bid] = make_float2(m_c, z_c);

  // ---- weighted tile sum: P_c[d] = sum_rows wgt[row]*x[row][d], from LDS fp16 ----
  f32x4 pacc = {0.f, 0.f, 0.f, 0.f};
  #pragma unroll
  for (int r = 0; r < 16; ++r){
    int row = w * 16 + r;
    float wgt = __shfl(wv, row);
    int byte = (row * 512 + lane * 8) ^ ((row & 7) << 4);
    union { _Float16 h[4]; uint2 u; } pk;
    pk.u = *reinterpret_cast<const uint2*>(Ab + byte);
    pacc[0] = fmaf(wgt, (float)pk.h[0], pacc[0]);
    pacc[1] = fmaf(wgt, (float)pk.h[1], pacc[1]);
    pacc[2] = fmaf(wgt, (float)pk.h[2], pacc[2]);
    pacc[3] = fmaf(wgt, (float)pk.h[3], pacc[3]);
  }
  red4[w][lane] = pacc;
  bar_lds();
  if (tid < 64){
    f32x4 r = red4[0][tid] + red4[1][tid] + red4[2][tid] + red4[3][tid];
    *reinterpret_cast<f32x4*>(Pbuf + (size_t)bid * 256 + tid * 4) = r;
  }
}

// ---------------- combine 64 chunks per b: flash-style merge + W2 scale ----------------
__global__ __launch_bounds__(256) void k_combine(const float* __restrict__ Pbuf,
    const float2* __restrict__ mz, const float* __restrict__ W2, float* __restrict__ out){
  int b = blockIdx.x, d = threadIdx.x;
  __shared__ float2 smz[64];
  if (d < 64) smz[d] = mz[b * 64 + d];
  __syncthreads();
  float M = smz[0].x;
  #pragma unroll
  for (int c = 1; c < 64; ++c) M = fmaxf(M, smz[c].x);
  float Z = 0.f, acc = 0.f;
  #pragma unroll 8
  for (int c = 0; c < 64; ++c){
    float e = __expf(smz[c].x - M);
    Z += smz[c].y * e;
    acc = fmaf(e, Pbuf[(size_t)(b * 64 + c) * 256 + d], acc);
  }
  out[b * 256 + d] = acc * W2[d] / Z;
}

extern "C" void kernel_launch(void* const* d_in, const int* in_sizes, int n_in,
                              void* d_out, int out_size, void* d_ws, size_t ws_size,
                              hipStream_t stream){
  const float* x_h    = (const float*)d_in[0];
  const float* x_hpre = (const float*)d_in[1];
  const float* W1     = (const float*)d_in[2];
  const float* W2     = (const float*)d_in[3];
  const float* gamma  = (const float*)d_in[4];
  const float* beta   = (const float*)d_in[5];
  const float* rmean  = (const float*)d_in[6];
  const float* rvar   = (const float*)d_in[7];
  float* out = (float*)d_out;

  char* ws = (char*)d_ws;
  _Float16* Bp = (_Float16*)(ws);            // 131072 B (fragment-ordered W1)
  float* bns   = (float*)(ws + 131072);      // 16 KB
  float* bnb   = (float*)(ws + 147456);      // 16 KB
  float* Pbuf  = (float*)(ws + 163840);      // 4 MB (64*64 chunks * 256 f32)
  float2* mzb  = (float2*)(ws + 4358144);    // 32 KB  (total ~4.4 MB)

  hipLaunchKernelGGL(k_prep,    dim3(256),  dim3(256), 0, stream, W1, gamma, beta, rmean, rvar, Bp, bns, bnb);
  hipLaunchKernelGGL(k_fused,   dim3(4096), dim3(256), 0, stream, x_h, x_hpre, Bp, bns, bnb, Pbuf, mzb);
  hipLaunchKernelGGL(k_combine, dim3(64),   dim3(256), 0, stream, Pbuf, mzb, W2, out);
}

// Round 12
// 111.915 us; speedup vs baseline: 1.3557x; 1.0841x over previous
//
#include <hip/hip_runtime.h>

#define BN_EPS 1e-5f

typedef _Float16 half8 __attribute__((ext_vector_type(8)));
typedef __fp16 fp16x2 __attribute__((ext_vector_type(2)));
typedef float f32x4 __attribute__((ext_vector_type(4)));

__device__ __forceinline__ float tanh_fast(float x){
  float e = __expf(2.0f * x);
  return 1.0f - 2.0f / (e + 1.0f);
}

// ---------------- prep: W1 -> fp16 in MFMA-fragment order + BN scale/shift ----------------
// Fragment (q,c): q = k-chunk (32 k each, 0..7), c = col-block (16 e each, 0..15).
// lane l = kg*16+lr holds 8 halves: e = c*16+lr, d = q*32+kg*8+j.
__global__ __launch_bounds__(256) void k_prep(const float* __restrict__ W1,
    const float* __restrict__ gamma, const float* __restrict__ beta,
    const float* __restrict__ rmean, const float* __restrict__ rvar,
    _Float16* __restrict__ Bp2, float* __restrict__ bns, float* __restrict__ bnb){
  int i = blockIdx.x * 256 + threadIdx.x;   // 0..65535
  int j  = i & 7;
  int l  = (i >> 3) & 63;
  int c  = (i >> 9) & 15;
  int q  = (i >> 13) & 7;
  int lr = l & 15, kg = l >> 4;
  int e  = c * 16 + lr;
  int d  = q * 32 + kg * 8 + j;
  Bp2[i] = (_Float16)W1[e * 256 + d];
  if (i < 4096){
    float sc = gamma[i] * rsqrtf(rvar[i] + BN_EPS);
    bns[i] = sc;
    bnb[i] = beta[i] - rmean[i] * sc;
  }
}

// ---------------- fused GEMM + BN + tanh + dot(x_h) + local softmax + weighted tile sum ----------------
// 512 thr (8 waves), BM=64 x BN=256, K=256, 4 steps of BK=64, depth-1 ISSUE-early.
// Wave w owns cols [w*32, w*32+32) -> acc[4][2] = 32 AGPR. Occupancy theory (R11):
// combined VGPR+AGPR must stay <=128 for 16 waves/CU; the 4-wave layout's 64-AGPR
// acc made that impossible. Full 64x256 fp16 tile in LDS (XOR swizzle) survives
// for the fused softmax-weighted sum epilogue.
__global__ __launch_bounds__(512) void k_fused(const float* __restrict__ xh,
    const float* __restrict__ xhpre, const _Float16* __restrict__ Bp,
    const float* __restrict__ bns, const float* __restrict__ bnb,
    float* __restrict__ Pbuf, float2* __restrict__ mz){
  constexpr int S = 4096, Dd = 256;
  const int bid = blockIdx.x;       // 64 b * 64 chunks
  const int b  = bid >> 6;
  const int s0 = (bid & 63) * 64;
  const int tid = threadIdx.x;
  const int lane = tid & 63;
  const int w = tid >> 6;        // 0..7: wave owns cols [w*32, w*32+32)
  const int kg = lane >> 4;      // 0..3
  const int lr = lane & 15;      // 0..15

  __shared__ _Float16 A[64 * 256];           // 32 KB, XOR-swizzled rows
  __shared__ float bnsc[64], bnsh[64];
  __shared__ float red[8][64];               // 2 KB
  __shared__ f32x4 red4[8][64];              // 8 KB
  char* Ab = (char*)A;

  if (tid < 64){ bnsc[tid] = bns[s0 + tid]; bnsh[tid] = bnb[s0 + tid]; }

  float xhv[2];
  #pragma unroll
  for (int nt = 0; nt < 2; ++nt) xhv[nt] = xh[b * 256 + w * 32 + nt * 16 + lr];

  const float* Abase = xhpre + ((size_t)b * S + s0) * Dd;
  const int srow = tid >> 3;        // 0..63
  const int s8   = tid & 7;         // 8 threads/row, 8 floats each

  // stage chunk c (64 rows x 64 floats): thread reads 8 floats of its row
#define ISSUE(buf, c) \
  buf[0] = *reinterpret_cast<const float4*>(Abase + (size_t)srow * Dd + (c) * 64 + s8 * 8); \
  buf[1] = *reinterpret_cast<const float4*>(Abase + (size_t)srow * Dd + (c) * 64 + s8 * 8 + 4);
#define CVTW(buf, c) \
  { \
    union { fp16x2 h2[4]; uint4 u; } pk; \
    pk.h2[0] = __builtin_amdgcn_cvt_pkrtz(buf[0].x, buf[0].y); \
    pk.h2[1] = __builtin_amdgcn_cvt_pkrtz(buf[0].z, buf[0].w); \
    pk.h2[2] = __builtin_amdgcn_cvt_pkrtz(buf[1].x, buf[1].y); \
    pk.h2[3] = __builtin_amdgcn_cvt_pkrtz(buf[1].z, buf[1].w); \
    int byte = (srow * 512 + (c) * 128 + s8 * 16) ^ ((srow & 7) << 4); \
    *reinterpret_cast<uint4*>(Ab + byte) = pk.u; \
  }

  // ---- prologue: stage chunk 0 ----
  float4 nv[2];
  ISSUE(nv, 0); CVTW(nv, 0);
  __syncthreads();

  f32x4 acc[4][2] = {};

  #pragma unroll
  for (int k0 = 0; k0 < 4; ++k0){
    // issue next chunk early (overlaps with this step's MFMAs)
    if (k0 < 3){ ISSUE(nv, k0 + 1); }

    #pragma unroll
    for (int kk = 0; kk < 2; ++kk){
      const int q = k0 * 2 + kk;
      half8 afr[4], bfr[2];
      #pragma unroll
      for (int nt = 0; nt < 2; ++nt)
        bfr[nt] = *reinterpret_cast<const half8*>(Bp + ((size_t)((q * 16 + w * 2 + nt) * 64 + lane)) * 8);
      #pragma unroll
      for (int mt = 0; mt < 4; ++mt){
        int row = mt * 16 + lr;
        int byte = (row * 512 + q * 64 + kg * 16) ^ ((row & 7) << 4);
        afr[mt] = *reinterpret_cast<const half8*>(Ab + byte);
      }
      __builtin_amdgcn_s_setprio(1);
      #pragma unroll
      for (int mt = 0; mt < 4; ++mt)
        #pragma unroll
        for (int nt = 0; nt < 2; ++nt)
          acc[mt][nt] = __builtin_amdgcn_mfma_f32_16x16x32_f16(afr[mt], bfr[nt], acc[mt][nt], 0, 0, 0);
      __builtin_amdgcn_s_setprio(0);
    }

    if (k0 < 3){ CVTW(nv, k0 + 1); }   // disjoint LDS columns vs step-k0 reads
    __syncthreads();
  }
#undef ISSUE
#undef CVTW

  // ---- a_t epilogue: BN + tanh + dot(x_h); reduce 16 cols (lr) per wave ----
  #pragma unroll
  for (int mt = 0; mt < 4; ++mt){
    #pragma unroll
    for (int r = 0; r < 4; ++r){
      int row = mt * 16 + kg * 4 + r;   // C/D: col=lane&15, row=(lane>>4)*4+reg
      float sc = bnsc[row], sh = bnsh[row];
      float sum = 0.f;
      #pragma unroll
      for (int nt = 0; nt < 2; ++nt){
        float hv = fmaf(acc[mt][nt][r], sc, sh);
        sum = fmaf(tanh_fast(hv), xhv[nt], sum);
      }
      sum += __shfl_xor(sum, 1);
      sum += __shfl_xor(sum, 2);
      sum += __shfl_xor(sum, 4);
      sum += __shfl_xor(sum, 8);
      if (lr == 0) red[w][row] = sum;
    }
  }
  __syncthreads();

  // ---- softmax stats, computed redundantly by ALL waves (no extra barrier) ----
  float v = red[0][lane] + red[1][lane] + red[2][lane] + red[3][lane]
          + red[4][lane] + red[5][lane] + red[6][lane] + red[7][lane];
  float m_c = v;
  #pragma unroll
  for (int o = 1; o < 64; o <<= 1) m_c = fmaxf(m_c, __shfl_xor(m_c, o));
  float wv = __expf(v - m_c);    // this lane's weight for s-row `lane`
  float z_c = wv;
  #pragma unroll
  for (int o = 1; o < 64; o <<= 1) z_c += __shfl_xor(z_c, o);
  if (tid == 0) mz[bid] = make_float2(m_c, z_c);

  // ---- weighted tile sum: P_c[d] = sum_rows wgt[row]*x[row][d], 8 rows per wave ----
  f32x4 pacc = {0.f, 0.f, 0.f, 0.f};
  #pragma unroll
  for (int r = 0; r < 8; ++r){
    int row = w * 8 + r;
    float wgt = __shfl(wv, row);
    int byte = (row * 512 + lane * 8) ^ ((row & 7) << 4);
    union { _Float16 h[4]; uint2 u; } pk;
    pk.u = *reinterpret_cast<const uint2*>(Ab + byte);
    pacc[0] = fmaf(wgt, (float)pk.h[0], pacc[0]);
    pacc[1] = fmaf(wgt, (float)pk.h[1], pacc[1]);
    pacc[2] = fmaf(wgt, (float)pk.h[2], pacc[2]);
    pacc[3] = fmaf(wgt, (float)pk.h[3], pacc[3]);
  }
  red4[w][lane] = pacc;
  __syncthreads();
  if (tid < 64){
    f32x4 r = red4[0][tid] + red4[1][tid] + red4[2][tid] + red4[3][tid]
            + red4[4][tid] + red4[5][tid] + red4[6][tid] + red4[7][tid];
    *reinterpret_cast<f32x4*>(Pbuf + (size_t)bid * 256 + tid * 4) = r;
  }
}

// ---------------- combine 64 chunks per b: flash-style merge + W2 scale ----------------
__global__ __launch_bounds__(256) void k_combine(const float* __restrict__ Pbuf,
    const float2* __restrict__ mz, const float* __restrict__ W2, float* __restrict__ out){
  int b = blockIdx.x, d = threadIdx.x;
  __shared__ float2 smz[64];
  if (d < 64) smz[d] = mz[b * 64 + d];
  __syncthreads();
  float M = smz[0].x;
  #pragma unroll
  for (int c = 1; c < 64; ++c) M = fmaxf(M, smz[c].x);
  float Z = 0.f, acc = 0.f;
  #pragma unroll 8
  for (int c = 0; c < 64; ++c){
    float e = __expf(smz[c].x - M);
    Z += smz[c].y * e;
    acc = fmaf(e, Pbuf[(size_t)(b * 64 + c) * 256 + d], acc);
  }
  out[b * 256 + d] = acc * W2[d] / Z;
}

extern "C" void kernel_launch(void* const* d_in, const int* in_sizes, int n_in,
                              void* d_out, int out_size, void* d_ws, size_t ws_size,
                              hipStream_t stream){
  const float* x_h    = (const float*)d_in[0];
  const float* x_hpre = (const float*)d_in[1];
  const float* W1     = (const float*)d_in[2];
  const float* W2     = (const float*)d_in[3];
  const float* gamma  = (const float*)d_in[4];
  const float* beta   = (const float*)d_in[5];
  const float* rmean  = (const float*)d_in[6];
  const float* rvar   = (const float*)d_in[7];
  float* out = (float*)d_out;

  char* ws = (char*)d_ws;
  _Float16* Bp = (_Float16*)(ws);            // 131072 B (fragment-ordered W1)
  float* bns   = (float*)(ws + 131072);      // 16 KB
  float* bnb   = (float*)(ws + 147456);      // 16 KB
  float* Pbuf  = (float*)(ws + 163840);      // 4 MB (64*64 chunks * 256 f32)
  float2* mzb  = (float2*)(ws + 4358144);    // 32 KB  (total ~4.4 MB)

  hipLaunchKernelGGL(k_prep,    dim3(256),  dim3(256), 0, stream, W1, gamma, beta, rmean, rvar, Bp, bns, bnb);
  hipLaunchKernelGGL(k_fused,   dim3(4096), dim3(512), 0, stream, x_h, x_hpre, Bp, bns, bnb, Pbuf, mzb);
  hipLaunchKernelGGL(k_combine, dim3(64),   dim3(256), 0, stream, Pbuf, mzb, W2, out);
}